// Round 8
// baseline (151.305 us; speedup 1.0000x reference)
//
#include <hip/hip_runtime.h>
#include <hip/hip_bf16.h>

#define SLEN 2048
#define BATCH 2
#define NHQ 16
#define NHKV 8
#define DIM 128
#define SEG 512              // rows per segment (= chunk)
#define NSEG (SLEN / SEG)    // 4

// dword sizes of the swizzled LDS tiles
#define KTD (64 * 64)        // K tile: 64 keys x 128 bf16 (16 KB)
#define VTD (128 * 32)       // V^T tile: 128 d x 64 bf16 (16 KB)

typedef __attribute__((ext_vector_type(8))) short bf16x8;
typedef __attribute__((ext_vector_type(4))) short bf16x4;
typedef __attribute__((ext_vector_type(4))) float f32x4;

static __device__ inline short f2bf(float f) {
    __hip_bfloat16 h = __float2bfloat16(f);
    return *reinterpret_cast<short*>(&h);
}
static __device__ inline unsigned pack_bf2(float lo, float hi) {
    unsigned a = (unsigned)(unsigned short)f2bf(lo);
    unsigned b = (unsigned)(unsigned short)f2bf(hi);
    return a | (b << 16);
}
static __device__ inline float fast_exp2(float x) {
#if __has_builtin(__builtin_amdgcn_exp2f)
    return __builtin_amdgcn_exp2f(x);
#else
    return __builtin_exp2f(x);
#endif
}
static __device__ inline f32x4 mfma16(bf16x4 a, bf16x4 b, f32x4 c) {
#if __has_builtin(__builtin_amdgcn_mfma_f32_16x16x16bf16_1k)
    return __builtin_amdgcn_mfma_f32_16x16x16bf16_1k(a, b, c, 0, 0, 0);
#else
    asm volatile("v_mfma_f32_16x16x16_bf16 %0, %1, %2, %0\n\ts_nop 7\n\ts_nop 7"
                 : "+v"(c) : "v"(a), "v"(b));
    return c;
#endif
}

#define GLDS(g, l) __builtin_amdgcn_global_load_lds( \
    (const __attribute__((address_space(1))) void*)(g), \
    (__attribute__((address_space(3))) void*)(l), 16, 0, 0)

// ---------------------------------------------------------------------------
// Prepass: (a) blocks 0..511: convert K -> bf16 [b][h][key][d] and V -> bf16
// TRANSPOSED [b][h][d][key] in workspace.  (b) blocks 512..527: prep_runs —
// run_start/run_end of the contiguous run of 1s containing s. rs=-1, re=-2 if
// mask[s]==0. bidir-allowed(q,k) <=> rs[q]>=0 && rs[q]==rs[k]
// ---------------------------------------------------------------------------
__global__ __launch_bounds__(256) void conv_kv(
    const float* __restrict__ K, const float* __restrict__ V,
    unsigned short* __restrict__ Kb, unsigned short* __restrict__ Vt,
    const int* __restrict__ mask, int* __restrict__ rs, int* __restrict__ re)
{
    __shared__ float vt_s[64 * 132];     // fp32 transpose tile
    __shared__ int   sm[SLEN];           // prep_runs branch
    const int blk = blockIdx.x;
    const int NCONV = BATCH * NHKV * (SLEN / 64);   // 512

    if (blk >= NCONV) {
        const int idx = blk - NCONV;
        const int b = idx >> 3, slice = idx & 7;
        const int* mb = mask + b * SLEN;
        for (int i = threadIdx.x; i < SLEN; i += 256) sm[i] = mb[i];
        __syncthreads();
        const int i = slice * 256 + threadIdx.x;
        int s0 = -1, e0 = -2;
        if (sm[i] == 1) {
            s0 = i; while (s0 > 0 && sm[s0 - 1] == 1) --s0;
            e0 = i; while (e0 < SLEN - 1 && sm[e0 + 1] == 1) ++e0;
        }
        rs[b * SLEN + i] = s0;
        re[b * SLEN + i] = e0;
        return;
    }

    const int st = blk & 31;             // 64-key tile
    const int h  = (blk >> 5) & 7;
    const int b  = blk >> 8;
    const int s0 = st * 64;
    const int sl = threadIdx.x >> 2;         // 0..63
    const int dq = (threadIdx.x & 3) * 32;   // 0,32,64,96

    // ---- K convert (coalesced both sides, no LDS) ----
    {
        const float* ksrc = K + (((size_t)(b * SLEN + s0 + sl) * NHKV + h) * DIM) + dq;
        unsigned short* kdst = Kb + (((size_t)(b * NHKV + h) * SLEN) + s0 + sl) * DIM + dq;
        #pragma unroll
        for (int i = 0; i < 4; ++i) {
            float4 a = ((const float4*)ksrc)[2 * i];
            float4 c = ((const float4*)ksrc)[2 * i + 1];
            ((uint4*)kdst)[i] = make_uint4(pack_bf2(a.x, a.y), pack_bf2(a.z, a.w),
                                           pack_bf2(c.x, c.y), pack_bf2(c.z, c.w));
        }
    }

    // ---- V transpose via LDS ----
    {
        const float* vsrc = V + (((size_t)(b * SLEN + s0 + sl) * NHKV + h) * DIM) + dq;
        float4* ld = (float4*)&vt_s[sl * 132 + dq];
        #pragma unroll
        for (int i = 0; i < 8; ++i) ld[i] = ((const float4*)vsrc)[i];
    }
    __syncthreads();
    #pragma unroll
    for (int pass = 0; pass < 2; ++pass) {
        const int dl = (threadIdx.x >> 2) + pass * 64;   // 0..127
        const int sw = (threadIdx.x & 3) * 16;           // 0,16,32,48
        unsigned pk[8];
        #pragma unroll
        for (int m = 0; m < 8; ++m)
            pk[m] = pack_bf2(vt_s[(sw + 2 * m) * 132 + dl],
                             vt_s[(sw + 2 * m + 1) * 132 + dl]);
        unsigned short* dst = Vt + (((size_t)(b * NHKV + h) * DIM) + dl) * SLEN + s0 + sw;
        ((uint4*)dst)[0] = make_uint4(pk[0], pk[1], pk[2], pk[3]);
        ((uint4*)dst)[1] = make_uint4(pk[4], pk[5], pk[6], pk[7]);
    }
}

// ---------------------------------------------------------------------------
// Band-block MFMA flash attention, no-max softmax, swapped QK^T, 32-row waves.
// Block = 256 thr = 4 waves; wave owns TWO 16-row groups (rows r0..r0+31).
// Each K-frag / V-frag is read from LDS ONCE and feeds MFMAs of BOTH groups
// -> LDS instructions per q-row HALVED (round-7 analysis: LDS issue rate was
// oversubscribed ~5:1 vs MFMA; this is the direct fix).
// Swapped QK: sfr[u] = mfma_16x16x32(K-frag, Q[u]-frag); lane n holds
// P[qrow=n][key=c*16+quad*4+g] = A-frag of v_mfma_f32_16x16x16_bf16.
// P: register -> cvt -> MFMA. No P LDS. Masks lane-local.
// K/V: global_load_lds dbuf, 16B-granule XOR swizzle (same involution as r7,
// re-divided for 256 threads: thread t stages rows (t>>4)+16p / (t>>3)+32p,
// row&15 / row&7 invariant -> identical src<->dst relation, read side
// unchanged). LDS 64 KB -> 2 blocks/CU = 8 waves/CU.
// __launch_bounds__(256,1): VGPR cap 256 (empirical cap=256/arg2); 2 blocks
// need 2xVGPR<=512 so occupancy unaffected up to 256 VGPR -> no spill risk.
// Grid 512 with complementary band quarters {3,2,0,1} (balanced makespan).
// ---------------------------------------------------------------------------
__global__ __launch_bounds__(256, 1) void attn_fwd(
    const float* __restrict__ Q, const unsigned short* __restrict__ KbP,
    const unsigned short* __restrict__ VtP, const int* __restrict__ rs,
    const int* __restrict__ re, const int* __restrict__ csp,
    float* __restrict__ Out)
{
    const int tid  = threadIdx.x;
    const int wid  = tid >> 6;     // 0..3
    const int lane = tid & 63;
    const int quad = lane >> 4;
    const int n    = lane & 15;

    // decode: h = xcd (per-XCD K/V = 2 MB L2); band quarters {3,2,0,1}
    const int bid   = blockIdx.x;          // 0..511
    const int h     = bid & 7;
    const int inner = (bid >> 3) & 15;
    const int q4    = (bid >> 7) & 3;
    const int band  = (q4 == 0) ? 3 : (q4 == 1) ? 2 : (q4 == 2) ? 0 : 1;
    const int b     = inner & 1;
    const int hq    = h * 2 + ((inner >> 1) & 1);
    const int chunk = inner >> 2;          // 0..3
    const int r0 = chunk * SEG + band * 128 + wid * 32;   // wave: rows r0..r0+31

    __shared__ unsigned pool[2 * KTD + 2 * VTD];   // 65536 B

    // 1/sqrt(128) * log2(e): fold exp->exp2 into Q scaling
    const float scale = 0.08838834764831845f * 1.4426950408889634f;
    const int cs = csp[0];

    const int* rsb = rs + b * SLEN;
    const int* reb = re + b * SLEN;

    // per-row info for both groups: lane n -> rows r0+n, r0+16+n
    const int row0 = r0 + n;
    const int row1 = r0 + 16 + n;
    const int rsv0 = rsb[row0];
    const int rsv1 = rsb[row1];
    const int csr0 = (row0 / cs) * cs;
    const int csr1 = (row1 / cs) * cs;
    int lo_rt, hi_rt;
    {
        const int rev0 = reb[row0];
        const int rev1 = reb[row1];
        int lo = min(csr0, csr1);
        if (rsv0 >= 0) lo = min(lo, rsv0);
        if (rsv1 >= 0) lo = min(lo, rsv1);
        int hi = max(max(row1, rev0), rev1);
        #pragma unroll
        for (int off = 8; off > 0; off >>= 1) {
            lo = min(lo, __shfl_xor(lo, off, 64));
            hi = max(hi, __shfl_xor(hi, off, 64));
        }
        lo_rt = lo; hi_rt = hi;
    }
    const int cshi0 = ((r0 + 15) / cs) * cs;
    const int cshi1 = ((r0 + 31) / cs) * cs;

    // Q B-frags (scaled): qa[u][kb] = Q[row r0+16u+n][d=kb*32+quad*8+j]
    bf16x8 qa[2][4];
    #pragma unroll
    for (int u = 0; u < 2; ++u) {
        const float* qp = Q + (((size_t)(b * SLEN + r0 + 16 * u + n) * NHQ + hq) * DIM) + quad * 8;
        #pragma unroll
        for (int kb = 0; kb < 4; ++kb) {
            float4 f0 = *(const float4*)(qp + kb * 32);
            float4 f1 = *(const float4*)(qp + kb * 32 + 4);
            bf16x8 a;
            a[0] = f2bf(f0.x * scale); a[1] = f2bf(f0.y * scale);
            a[2] = f2bf(f0.z * scale); a[3] = f2bf(f0.w * scale);
            a[4] = f2bf(f1.x * scale); a[5] = f2bf(f1.y * scale);
            a[6] = f2bf(f1.z * scale); a[7] = f2bf(f1.w * scale);
            qa[u][kb] = a;
        }
    }

    // block k-range = union over 4 waves (through pool, pre-staging)
    int lo_blk, hi_blk;
    {
        int* sred = (int*)pool;
        if (lane == 0) { sred[wid * 2] = lo_rt; sred[wid * 2 + 1] = hi_rt; }
        __syncthreads();
        int lo = 0x7fffffff, hi = 0;
        #pragma unroll
        for (int i = 0; i < 4; ++i) {
            lo = min(lo, sred[2 * i]);
            hi = max(hi, sred[2 * i + 1]);
        }
        __syncthreads();
        lo_blk = lo & ~63;
        hi_blk = hi;
    }

    float lrow[2] = {0.f, 0.f};
    f32x4 o[2][8];
    #pragma unroll
    for (int u = 0; u < 2; ++u)
        #pragma unroll
        for (int nb = 0; nb < 8; ++nb) o[u][nb] = (f32x4){0.f, 0.f, 0.f, 0.f};

    const unsigned short* KbB = KbP + (size_t)(b * NHKV + h) * SLEN * DIM;
    const unsigned short* VtB = VtP + (size_t)(b * NHKV + h) * DIM * SLEN;

    // staging: pre-swizzled source offsets (16B granules; 256 threads x 4)
    const int ksl  = (tid & 15) ^ ((tid >> 4) & 15);
    const size_t koff = (size_t)(tid >> 4) * DIM + ksl * 8;
    const int vsl  = (tid & 7) ^ ((tid >> 3) & 7);
    const size_t voff = (size_t)(tid >> 3) * SLEN + vsl * 8;

    int rsv_c;
    // ---- prime: stage tile0 into buf0 ----
    {
        const unsigned short* ks = KbB + (size_t)lo_blk * DIM + koff;
        const unsigned short* vs = VtB + lo_blk + voff;
        char* kl = (char*)pool;
        char* vl = (char*)pool + 32768;
        #pragma unroll
        for (int p = 0; p < 4; ++p) {
            GLDS(ks + (size_t)(p * 16) * DIM,  kl + tid * 16 + p * 4096);
            GLDS(vs + (size_t)(p * 32) * SLEN, vl + tid * 16 + p * 4096);
        }
        rsv_c = rsb[lo_blk + lane];
    }
    __syncthreads();   // drains vmcnt -> buf0 ready

    int bufi = 0;
    for (int k0 = lo_blk; k0 <= hi_blk; k0 += 64, bufi ^= 1) {
        // ---- issue stage for next tile into buf^1 ----
        int rsv_n = rsv_c;
        if (k0 + 64 <= hi_blk) {
            const int kn0 = k0 + 64;
            const unsigned short* ks = KbB + (size_t)kn0 * DIM + koff;
            const unsigned short* vs = VtB + kn0 + voff;
            char* kl = (char*)pool + (bufi ^ 1) * 16384;
            char* vl = (char*)pool + 32768 + (bufi ^ 1) * 16384;
            #pragma unroll
            for (int p = 0; p < 4; ++p) {
                GLDS(ks + (size_t)(p * 16) * DIM,  kl + tid * 16 + p * 4096);
                GLDS(vs + (size_t)(p * 32) * SLEN, vl + tid * 16 + p * 4096);
            }
            rsv_n = rsb[kn0 + lane];
        }

        if ((k0 + 63 >= lo_rt) && (k0 <= hi_rt)) {
            const short* ktb = (const short*)(pool + bufi * KTD);
            const short* vtb = (const short*)(pool + 2 * KTD + bufi * VTD);

            // ---- S^T = mfma(K, Q[u]): each K-frag read ONCE, feeds both ----
            f32x4 sfr[2][4];
            #pragma unroll
            for (int u = 0; u < 2; ++u)
                #pragma unroll
                for (int c = 0; c < 4; ++c) sfr[u][c] = (f32x4){0.f, 0.f, 0.f, 0.f};
            __builtin_amdgcn_s_setprio(1);
            #pragma unroll
            for (int c = 0; c < 4; ++c) {
                #pragma unroll
                for (int kb = 0; kb < 4; ++kb) {
                    const bf16x8 kf = *(const bf16x8*)(ktb +
                        (c * 16 + n) * DIM + (((kb * 4 + quad) ^ n) * 8));
                    sfr[0][c] = __builtin_amdgcn_mfma_f32_16x16x32_bf16(kf, qa[0][kb], sfr[0][c], 0, 0, 0);
                    sfr[1][c] = __builtin_amdgcn_mfma_f32_16x16x32_bf16(kf, qa[1][kb], sfr[1][c], 0, 0, 0);
                }
            }
            __builtin_amdgcn_s_setprio(0);

            // ---- mask (lane-local rows; rs[key] shuffled once per (c,g)) ----
            const bool f0 = (k0 >= cshi0) && (k0 + 63 <= r0);
            const bool f1 = (k0 >= cshi1) && (k0 + 63 <= r0 + 16);
            if (!(f0 && f1)) {
                #pragma unroll
                for (int c = 0; c < 4; ++c) {
                    #pragma unroll
                    for (int g = 0; g < 4; ++g) {
                        const int kcl  = k0 + c * 16 + quad * 4 + g;
                        const int rskv = __shfl(rsv_c, c * 16 + quad * 4 + g, 64);
                        if (!f0) {
                            const bool ok = ((kcl >= csr0) && (kcl <= row0)) ||
                                            (rsv0 >= 0 && rskv == rsv0);
                            if (!ok) sfr[0][c][g] = -3.0e38f;
                        }
                        if (!f1) {
                            const bool ok = ((kcl >= csr1) && (kcl <= row1)) ||
                                            (rsv1 >= 0 && rskv == rsv1);
                            if (!ok) sfr[1][c][g] = -3.0e38f;
                        }
                    }
                }
            }

            // ---- p = exp2(s): registers only; pack to A-frags ----
            bf16x4 pa[2][4];
            #pragma unroll
            for (int u = 0; u < 2; ++u) {
                #pragma unroll
                for (int c = 0; c < 4; ++c) {
                    float p0 = fast_exp2(sfr[u][c][0]);
                    float p1 = fast_exp2(sfr[u][c][1]);
                    float p2 = fast_exp2(sfr[u][c][2]);
                    float p3 = fast_exp2(sfr[u][c][3]);
                    lrow[u] += (p0 + p1) + (p2 + p3);
                    uint2 ww = make_uint2(pack_bf2(p0, p1), pack_bf2(p2, p3));
                    pa[u][c] = __builtin_bit_cast(bf16x4, ww);
                }
            }

            // ---- O += P V: each V-frag read ONCE, feeds both groups ----
            __builtin_amdgcn_s_setprio(1);
            #pragma unroll
            for (int c = 0; c < 4; ++c) {
                #pragma unroll
                for (int nb = 0; nb < 8; ++nb) {
                    const bf16x4 vb = *(const bf16x4*)(vtb +
                        (nb * 16 + n) * 64 + (((c * 2 + (quad >> 1)) ^ (n & 7)) * 8)
                        + (quad & 1) * 4);
                    o[0][nb] = mfma16(pa[0][c], vb, o[0][nb]);
                    o[1][nb] = mfma16(pa[1][c], vb, o[1][nb]);
                }
            }
            __builtin_amdgcn_s_setprio(0);
        }

        __syncthreads();   // drains next-tile loads; releases buf[bufi]
        rsv_c = rsv_n;
    }

    // ---- epilogue: per-group row-sum over quads, redistribute inv, store ----
    #pragma unroll
    for (int u = 0; u < 2; ++u) {
        float l = lrow[u];
        l += __shfl_xor(l, 16, 64);
        l += __shfl_xor(l, 32, 64);
        const float inv = 1.0f / l;      // lane holds inv for row r0+16u+n
        #pragma unroll
        for (int g = 0; g < 4; ++g) {
            const float invg = __shfl(inv, quad * 4 + g, 64);
            const int r = r0 + 16 * u + quad * 4 + g;
            float* op = Out + ((size_t)(b * SLEN + r) * NHQ + hq) * DIM + n;
            #pragma unroll
            for (int nb = 0; nb < 8; ++nb)
                op[nb * 16] = o[u][nb][g] * invg;
        }
    }
}

extern "C" void kernel_launch(void* const* d_in, const int* in_sizes, int n_in,
                              void* d_out, int out_size, void* d_ws, size_t ws_size,
                              hipStream_t stream) {
    const float* q  = (const float*)d_in[0];
    const float* k  = (const float*)d_in[1];
    const float* v  = (const float*)d_in[2];
    const int*   bm = (const int*)d_in[3];
    const int*   cs = (const int*)d_in[4];
    float* out = (float*)d_out;

    int* rs = (int*)d_ws;
    int* re = rs + BATCH * SLEN;
    unsigned short* Kb = (unsigned short*)((char*)d_ws + 32768);
    unsigned short* Vt = Kb + (size_t)BATCH * NHKV * SLEN * DIM;

    hipLaunchKernelGGL(conv_kv, dim3(BATCH * NHKV * (SLEN / 64) + BATCH * 8), dim3(256),
                       0, stream, k, v, Kb, Vt, bm, rs, re);
    hipLaunchKernelGGL(attn_fwd, dim3(512), dim3(256), 0, stream,
                       q, Kb, Vt, rs, re, cs, out);
}

// Round 9
// 131.649 us; speedup vs baseline: 1.1493x; 1.1493x over previous
//
#include <hip/hip_runtime.h>
#include <hip/hip_bf16.h>

#define SLEN 2048
#define BATCH 2
#define NHQ 16
#define NHKV 8
#define DIM 128
#define SEG 512              // rows per segment (= chunk)
#define NSEG (SLEN / SEG)    // 4

// dword sizes of the swizzled LDS tiles
#define KTD (64 * 64)        // K tile: 64 keys x 128 bf16 (16 KB)
#define VTD (128 * 32)       // V^T tile: 128 d x 64 bf16 (16 KB)

typedef __attribute__((ext_vector_type(8))) short bf16x8;
typedef __attribute__((ext_vector_type(4))) short bf16x4;
typedef __attribute__((ext_vector_type(4))) float f32x4;

static __device__ inline short f2bf(float f) {
    __hip_bfloat16 h = __float2bfloat16(f);
    return *reinterpret_cast<short*>(&h);
}
static __device__ inline unsigned pack_bf2(float lo, float hi) {
    unsigned a = (unsigned)(unsigned short)f2bf(lo);
    unsigned b = (unsigned)(unsigned short)f2bf(hi);
    return a | (b << 16);
}
static __device__ inline float fast_exp2(float x) {
#if __has_builtin(__builtin_amdgcn_exp2f)
    return __builtin_amdgcn_exp2f(x);
#else
    return __builtin_exp2f(x);
#endif
}
static __device__ inline f32x4 mfma16(bf16x4 a, bf16x4 b, f32x4 c) {
#if __has_builtin(__builtin_amdgcn_mfma_f32_16x16x16bf16_1k)
    return __builtin_amdgcn_mfma_f32_16x16x16bf16_1k(a, b, c, 0, 0, 0);
#else
    asm volatile("v_mfma_f32_16x16x16_bf16 %0, %1, %2, %0\n\ts_nop 7\n\ts_nop 7"
                 : "+v"(c) : "v"(a), "v"(b));
    return c;
#endif
}

#define GLDS(g, l) __builtin_amdgcn_global_load_lds( \
    (const __attribute__((address_space(1))) void*)(g), \
    (__attribute__((address_space(3))) void*)(l), 16, 0, 0)

// ---------------------------------------------------------------------------
// Prepass: (a) blocks 0..511: convert K -> bf16 [b][h][key][d] and V -> bf16
// TRANSPOSED [b][h][d][key] in workspace.  (b) blocks 512..527: prep_runs —
// run_start/run_end of the contiguous run of 1s containing s. rs=-1, re=-2 if
// mask[s]==0. bidir-allowed(q,k) <=> rs[q]>=0 && rs[q]==rs[k]
// ---------------------------------------------------------------------------
__global__ __launch_bounds__(256) void conv_kv(
    const float* __restrict__ K, const float* __restrict__ V,
    unsigned short* __restrict__ Kb, unsigned short* __restrict__ Vt,
    const int* __restrict__ mask, int* __restrict__ rs, int* __restrict__ re)
{
    __shared__ float vt_s[64 * 132];     // fp32 transpose tile
    __shared__ int   sm[SLEN];           // prep_runs branch
    const int blk = blockIdx.x;
    const int NCONV = BATCH * NHKV * (SLEN / 64);   // 512

    if (blk >= NCONV) {
        const int idx = blk - NCONV;
        const int b = idx >> 3, slice = idx & 7;
        const int* mb = mask + b * SLEN;
        for (int i = threadIdx.x; i < SLEN; i += 256) sm[i] = mb[i];
        __syncthreads();
        const int i = slice * 256 + threadIdx.x;
        int s0 = -1, e0 = -2;
        if (sm[i] == 1) {
            s0 = i; while (s0 > 0 && sm[s0 - 1] == 1) --s0;
            e0 = i; while (e0 < SLEN - 1 && sm[e0 + 1] == 1) ++e0;
        }
        rs[b * SLEN + i] = s0;
        re[b * SLEN + i] = e0;
        return;
    }

    const int st = blk & 31;             // 64-key tile
    const int h  = (blk >> 5) & 7;
    const int b  = blk >> 8;
    const int s0 = st * 64;
    const int sl = threadIdx.x >> 2;         // 0..63
    const int dq = (threadIdx.x & 3) * 32;   // 0,32,64,96

    // ---- K convert (coalesced both sides, no LDS) ----
    {
        const float* ksrc = K + (((size_t)(b * SLEN + s0 + sl) * NHKV + h) * DIM) + dq;
        unsigned short* kdst = Kb + (((size_t)(b * NHKV + h) * SLEN) + s0 + sl) * DIM + dq;
        #pragma unroll
        for (int i = 0; i < 4; ++i) {
            float4 a = ((const float4*)ksrc)[2 * i];
            float4 c = ((const float4*)ksrc)[2 * i + 1];
            ((uint4*)kdst)[i] = make_uint4(pack_bf2(a.x, a.y), pack_bf2(a.z, a.w),
                                           pack_bf2(c.x, c.y), pack_bf2(c.z, c.w));
        }
    }

    // ---- V transpose via LDS ----
    {
        const float* vsrc = V + (((size_t)(b * SLEN + s0 + sl) * NHKV + h) * DIM) + dq;
        float4* ld = (float4*)&vt_s[sl * 132 + dq];
        #pragma unroll
        for (int i = 0; i < 8; ++i) ld[i] = ((const float4*)vsrc)[i];
    }
    __syncthreads();
    #pragma unroll
    for (int pass = 0; pass < 2; ++pass) {
        const int dl = (threadIdx.x >> 2) + pass * 64;   // 0..127
        const int sw = (threadIdx.x & 3) * 16;           // 0,16,32,48
        unsigned pk[8];
        #pragma unroll
        for (int m = 0; m < 8; ++m)
            pk[m] = pack_bf2(vt_s[(sw + 2 * m) * 132 + dl],
                             vt_s[(sw + 2 * m + 1) * 132 + dl]);
        unsigned short* dst = Vt + (((size_t)(b * NHKV + h) * DIM) + dl) * SLEN + s0 + sw;
        ((uint4*)dst)[0] = make_uint4(pk[0], pk[1], pk[2], pk[3]);
        ((uint4*)dst)[1] = make_uint4(pk[4], pk[5], pk[6], pk[7]);
    }
}

// ---------------------------------------------------------------------------
// Merged-head band-block MFMA flash attention (round-7 structure restored:
// 8 waves x 16 rows x 512 thr -- rounds 1/3/8 proved TLP > per-wave
// efficiency for this latency-bound kernel).
// Block = one 64-row band serving BOTH q-heads of a KV head: 8 waves =
// 2 hq x 4 sixteen-row tiles. vs round 7: k-tiles per (b,h,chunk) 40 -> 36,
// k-range union spans 64 rows not 128 (tighter run extensions), K/V staging
// shared by both heads. Complementary band pairing: bid & bid+256 get bands
// 7-ps & ps (sum const) -> balanced per-CU makespan.
// Swapped QK: sfr = mfma_16x16x32(K-frag, Q-frag) -> lane n holds
// P[qrow=n][key=c*16+quad*4+g] = A-frag of v_mfma_f32_16x16x16_bf16.
// P: register -> cvt -> MFMA. No P LDS. Masks lane-local.
// K/V: global_load_lds dbuf, 16B-granule XOR swizzle (pre-swizzled source,
// same XOR on read). LDS 64 KB -> 2 blocks/CU = 16 waves/CU.
// __launch_bounds__(512,2): empirical VGPR cap = 256/arg2 = 128, no spills.
// ---------------------------------------------------------------------------
__global__ __launch_bounds__(512, 2) void attn_fwd(
    const float* __restrict__ Q, const unsigned short* __restrict__ KbP,
    const unsigned short* __restrict__ VtP, const int* __restrict__ rs,
    const int* __restrict__ re, const int* __restrict__ csp,
    float* __restrict__ Out)
{
    const int tid  = threadIdx.x;
    const int wid  = tid >> 6;     // 0..7
    const int lane = tid & 63;
    const int quad = lane >> 4;
    const int n    = lane & 15;

    // decode: h = xcd (per-XCD K/V = 2 MB L2); bands paired 7-ps <-> ps
    const int bid   = blockIdx.x;          // 0..511
    const int h     = bid & 7;
    const int b     = (bid >> 3) & 1;
    const int chunk = (bid >> 4) & 3;
    const int ps    = (bid >> 6) & 3;
    const int sel   = (bid >> 8) & 1;
    const int band  = sel ? ps : 7 - ps;
    const int hq    = h * 2 + (wid & 1);   // wave-level head select
    const int wt    = wid >> 1;            // 0..3: 16-row tile within band
    const int r0 = chunk * SEG + band * 64 + wt * 16;

    __shared__ unsigned pool[2 * KTD + 2 * VTD];   // 65536 B

    // 1/sqrt(128) * log2(e): fold exp->exp2 into Q scaling
    const float scale = 0.08838834764831845f * 1.4426950408889634f;
    const int cs = csp[0];

    const int* rsb = rs + b * SLEN;
    const int* reb = re + b * SLEN;

    // per-row info: lane n -> row r0+n (duplicated across quads)
    const int row  = r0 + n;
    const int rsvq = rsb[row];
    const int csrq = (row / cs) * cs;
    int lo_rt, hi_rt;
    {
        const int revq = reb[row];
        int lo = csrq; if (rsvq >= 0 && rsvq < lo) lo = rsvq;
        int hi = row;  if (revq > hi) hi = revq;
        #pragma unroll
        for (int off = 8; off > 0; off >>= 1) {
            lo = min(lo, __shfl_xor(lo, off, 64));
            hi = max(hi, __shfl_xor(hi, off, 64));
        }
        lo_rt = lo; hi_rt = hi;
    }
    const int cshi = ((r0 + 15) / cs) * cs;

    // Q B-frags (scaled): qa[kb] holds Q[row n][d=kb*32+quad*8+j]
    bf16x8 qa[4];
    {
        const float* qp = Q + (((size_t)(b * SLEN + row) * NHQ + hq) * DIM) + quad * 8;
        #pragma unroll
        for (int kb = 0; kb < 4; ++kb) {
            float4 f0 = *(const float4*)(qp + kb * 32);
            float4 f1 = *(const float4*)(qp + kb * 32 + 4);
            bf16x8 a;
            a[0] = f2bf(f0.x * scale); a[1] = f2bf(f0.y * scale);
            a[2] = f2bf(f0.z * scale); a[3] = f2bf(f0.w * scale);
            a[4] = f2bf(f1.x * scale); a[5] = f2bf(f1.y * scale);
            a[6] = f2bf(f1.z * scale); a[7] = f2bf(f1.w * scale);
            qa[kb] = a;
        }
    }

    // block k-range = union over 8 waves (through pool, pre-staging)
    int lo_blk, hi_blk;
    {
        int* sred = (int*)pool;
        if (lane == 0) { sred[wid * 2] = lo_rt; sred[wid * 2 + 1] = hi_rt; }
        __syncthreads();
        int lo = 0x7fffffff, hi = 0;
        #pragma unroll
        for (int i = 0; i < 8; ++i) {
            lo = min(lo, sred[2 * i]);
            hi = max(hi, sred[2 * i + 1]);
        }
        __syncthreads();
        lo_blk = lo & ~63;
        hi_blk = hi;
    }

    float lrow = 0.0f;
    f32x4 o[8];
    #pragma unroll
    for (int nb = 0; nb < 8; ++nb) o[nb] = (f32x4){0.f, 0.f, 0.f, 0.f};

    const unsigned short* KbB = KbP + (size_t)(b * NHKV + h) * SLEN * DIM;
    const unsigned short* VtB = VtP + (size_t)(b * NHKV + h) * DIM * SLEN;

    // staging: per-thread pre-swizzled source offsets (16B granule involution)
    const int kr0  = tid >> 4;                       // K rows 0..31 (+32)
    const int ksl  = (tid & 15) ^ (kr0 & 15);
    const size_t koff = (size_t)kr0 * DIM + ksl * 8;
    const int vr0  = tid >> 3;                       // V rows 0..63 (+64)
    const int vsl  = (tid & 7) ^ (vr0 & 7);
    const size_t voff = (size_t)vr0 * SLEN + vsl * 8;

    int rsv_c;
    // ---- prime: stage tile0 into buf0 ----
    {
        const unsigned short* ks = KbB + (size_t)lo_blk * DIM + koff;
        const unsigned short* vs = VtB + lo_blk + voff;
        char* kl = (char*)pool;
        char* vl = (char*)pool + 32768;
        GLDS(ks,                     kl + tid * 16);
        GLDS(ks + (size_t)32 * DIM,  kl + 8192 + tid * 16);
        GLDS(vs,                     vl + tid * 16);
        GLDS(vs + (size_t)64 * SLEN, vl + 8192 + tid * 16);
        rsv_c = rsb[lo_blk + lane];
    }
    __syncthreads();   // drains vmcnt -> buf0 ready

    int bufi = 0;
    for (int k0 = lo_blk; k0 <= hi_blk; k0 += 64, bufi ^= 1) {
        // ---- issue stage for next tile into buf^1 ----
        int rsv_n = rsv_c;
        if (k0 + 64 <= hi_blk) {
            const int kn0 = k0 + 64;
            const unsigned short* ks = KbB + (size_t)kn0 * DIM + koff;
            const unsigned short* vs = VtB + kn0 + voff;
            char* kl = (char*)pool + (bufi ^ 1) * 16384;
            char* vl = (char*)pool + 32768 + (bufi ^ 1) * 16384;
            GLDS(ks,                     kl + tid * 16);
            GLDS(ks + (size_t)32 * DIM,  kl + 8192 + tid * 16);
            GLDS(vs,                     vl + tid * 16);
            GLDS(vs + (size_t)64 * SLEN, vl + 8192 + tid * 16);
            rsv_n = rsb[kn0 + lane];
        }

        if ((k0 + 63 >= lo_rt) && (k0 <= hi_rt)) {
            const short* ktb = (const short*)(pool + bufi * KTD);
            const short* vtb = (const short*)(pool + 2 * KTD + bufi * VTD);

            // ---- S^T = mfma(K,Q): sfr[c][g] = S[qrow n][key k0+c*16+quad*4+g]
            f32x4 sfr[4];
            #pragma unroll
            for (int c = 0; c < 4; ++c) sfr[c] = (f32x4){0.f, 0.f, 0.f, 0.f};
            __builtin_amdgcn_s_setprio(1);
            #pragma unroll
            for (int c = 0; c < 4; ++c) {
                #pragma unroll
                for (int kb = 0; kb < 4; ++kb) {
                    const bf16x8 kf = *(const bf16x8*)(ktb +
                        (c * 16 + n) * DIM + (((kb * 4 + quad) ^ n) * 8));
                    sfr[c] = __builtin_amdgcn_mfma_f32_16x16x32_bf16(kf, qa[kb], sfr[c], 0, 0, 0);
                }
            }
            __builtin_amdgcn_s_setprio(0);

            // ---- mask (lane-local row; gather rs[key] by shuffle) ----
            const bool fullc = (k0 >= cshi) && (k0 + 63 <= r0);
            if (!fullc) {
                #pragma unroll
                for (int c = 0; c < 4; ++c) {
                    #pragma unroll
                    for (int g = 0; g < 4; ++g) {
                        const int kcl  = k0 + c * 16 + quad * 4 + g;
                        const int rskv = __shfl(rsv_c, c * 16 + quad * 4 + g, 64);
                        const bool ok = ((kcl >= csrq) && (kcl <= row)) ||
                                        (rsvq >= 0 && rskv == rsvq);
                        if (!ok) sfr[c][g] = -3.0e38f;   // exp2 -> 0
                    }
                }
            }

            // ---- p = exp2(s): registers only; pack to A-frags ----
            bf16x4 pa[4];
            #pragma unroll
            for (int c = 0; c < 4; ++c) {
                float p0 = fast_exp2(sfr[c][0]);
                float p1 = fast_exp2(sfr[c][1]);
                float p2 = fast_exp2(sfr[c][2]);
                float p3 = fast_exp2(sfr[c][3]);
                lrow += (p0 + p1) + (p2 + p3);
                uint2 ww = make_uint2(pack_bf2(p0, p1), pack_bf2(p2, p3));
                pa[c] = __builtin_bit_cast(bf16x4, ww);
            }

            // ---- O += P V via 16x16x16 (A = registers, B = V^T from LDS) ----
            __builtin_amdgcn_s_setprio(1);
            #pragma unroll
            for (int c = 0; c < 4; ++c) {
                #pragma unroll
                for (int nb = 0; nb < 8; ++nb) {
                    const bf16x4 vb = *(const bf16x4*)(vtb +
                        (nb * 16 + n) * 64 + (((c * 2 + (quad >> 1)) ^ (n & 7)) * 8)
                        + (quad & 1) * 4);
                    o[nb] = mfma16(pa[c], vb, o[nb]);
                }
            }
            __builtin_amdgcn_s_setprio(0);
        }

        __syncthreads();   // drains next-tile loads; releases buf[bufi]
        rsv_c = rsv_n;
    }

    // ---- epilogue: row-sum over quads, redistribute inv, store ----
    lrow += __shfl_xor(lrow, 16, 64);
    lrow += __shfl_xor(lrow, 32, 64);
    const float inv = 1.0f / lrow;     // lane holds inv for row n
    #pragma unroll
    for (int g = 0; g < 4; ++g) {
        const float invg = __shfl(inv, quad * 4 + g, 64);
        const int r = r0 + quad * 4 + g;
        float* op = Out + ((size_t)(b * SLEN + r) * NHQ + hq) * DIM + n;
        #pragma unroll
        for (int nb = 0; nb < 8; ++nb)
            op[nb * 16] = o[nb][g] * invg;
    }
}

extern "C" void kernel_launch(void* const* d_in, const int* in_sizes, int n_in,
                              void* d_out, int out_size, void* d_ws, size_t ws_size,
                              hipStream_t stream) {
    const float* q  = (const float*)d_in[0];
    const float* k  = (const float*)d_in[1];
    const float* v  = (const float*)d_in[2];
    const int*   bm = (const int*)d_in[3];
    const int*   cs = (const int*)d_in[4];
    float* out = (float*)d_out;

    int* rs = (int*)d_ws;
    int* re = rs + BATCH * SLEN;
    unsigned short* Kb = (unsigned short*)((char*)d_ws + 32768);
    unsigned short* Vt = Kb + (size_t)BATCH * NHKV * SLEN * DIM;

    hipLaunchKernelGGL(conv_kv, dim3(BATCH * NHKV * (SLEN / 64) + BATCH * 8), dim3(256),
                       0, stream, k, v, Kb, Vt, bm, rs, re);
    hipLaunchKernelGGL(attn_fwd, dim3(512), dim3(512), 0, stream,
                       q, Kb, Vt, rs, re, cs, out);
}

// Round 10
// 130.161 us; speedup vs baseline: 1.1624x; 1.0114x over previous
//
#include <hip/hip_runtime.h>
#include <hip/hip_bf16.h>

#define SLEN 2048
#define BATCH 2
#define NHQ 16
#define NHKV 8
#define DIM 128
#define SEG 512              // rows per segment (= chunk)
#define NSEG (SLEN / SEG)    // 4

// dword sizes of the swizzled LDS tiles
#define KTD (64 * 64)        // K tile: 64 keys x 128 bf16 (16 KB)
#define VTD (128 * 32)       // V^T tile: 128 d x 64 bf16 (16 KB)

typedef __attribute__((ext_vector_type(8))) short bf16x8;
typedef __attribute__((ext_vector_type(4))) short bf16x4;
typedef __attribute__((ext_vector_type(4))) float f32x4;

static __device__ inline short f2bf(float f) {
    __hip_bfloat16 h = __float2bfloat16(f);
    return *reinterpret_cast<short*>(&h);
}
static __device__ inline unsigned pack_bf2(float lo, float hi) {
    unsigned a = (unsigned)(unsigned short)f2bf(lo);
    unsigned b = (unsigned)(unsigned short)f2bf(hi);
    return a | (b << 16);
}
static __device__ inline float fast_exp2(float x) {
#if __has_builtin(__builtin_amdgcn_exp2f)
    return __builtin_amdgcn_exp2f(x);
#else
    return __builtin_exp2f(x);
#endif
}
static __device__ inline f32x4 mfma16(bf16x4 a, bf16x4 b, f32x4 c) {
#if __has_builtin(__builtin_amdgcn_mfma_f32_16x16x16bf16_1k)
    return __builtin_amdgcn_mfma_f32_16x16x16bf16_1k(a, b, c, 0, 0, 0);
#else
    asm volatile("v_mfma_f32_16x16x16_bf16 %0, %1, %2, %0\n\ts_nop 7\n\ts_nop 7"
                 : "+v"(c) : "v"(a), "v"(b));
    return c;
#endif
}

#define GLDS(g, l) __builtin_amdgcn_global_load_lds( \
    (const __attribute__((address_space(1))) void*)(g), \
    (__attribute__((address_space(3))) void*)(l), 16, 0, 0)

// ---------------------------------------------------------------------------
// Prepass: (a) blocks 0..511: convert K -> bf16 [b][h][key][d] and V -> bf16
// TRANSPOSED [b][h][d][key] in workspace.  (b) blocks 512..527: prep_runs —
// run_start/run_end of the contiguous run of 1s containing s. rs=-1, re=-2 if
// mask[s]==0.
// ---------------------------------------------------------------------------
__global__ __launch_bounds__(256) void conv_kv(
    const float* __restrict__ K, const float* __restrict__ V,
    unsigned short* __restrict__ Kb, unsigned short* __restrict__ Vt,
    const int* __restrict__ mask, int* __restrict__ rs, int* __restrict__ re)
{
    __shared__ float vt_s[64 * 132];     // fp32 transpose tile
    __shared__ int   sm[SLEN];           // prep_runs branch
    const int blk = blockIdx.x;
    const int NCONV = BATCH * NHKV * (SLEN / 64);   // 512

    if (blk >= NCONV) {
        const int idx = blk - NCONV;
        const int b = idx >> 3, slice = idx & 7;
        const int* mb = mask + b * SLEN;
        for (int i = threadIdx.x; i < SLEN; i += 256) sm[i] = mb[i];
        __syncthreads();
        const int i = slice * 256 + threadIdx.x;
        int s0 = -1, e0 = -2;
        if (sm[i] == 1) {
            s0 = i; while (s0 > 0 && sm[s0 - 1] == 1) --s0;
            e0 = i; while (e0 < SLEN - 1 && sm[e0 + 1] == 1) ++e0;
        }
        rs[b * SLEN + i] = s0;
        re[b * SLEN + i] = e0;
        return;
    }

    const int st = blk & 31;             // 64-key tile
    const int h  = (blk >> 5) & 7;
    const int b  = blk >> 8;
    const int s0 = st * 64;
    const int sl = threadIdx.x >> 2;         // 0..63
    const int dq = (threadIdx.x & 3) * 32;   // 0,32,64,96

    // ---- K convert (coalesced both sides, no LDS) ----
    {
        const float* ksrc = K + (((size_t)(b * SLEN + s0 + sl) * NHKV + h) * DIM) + dq;
        unsigned short* kdst = Kb + (((size_t)(b * NHKV + h) * SLEN) + s0 + sl) * DIM + dq;
        #pragma unroll
        for (int i = 0; i < 4; ++i) {
            float4 a = ((const float4*)ksrc)[2 * i];
            float4 c = ((const float4*)ksrc)[2 * i + 1];
            ((uint4*)kdst)[i] = make_uint4(pack_bf2(a.x, a.y), pack_bf2(a.z, a.w),
                                           pack_bf2(c.x, c.y), pack_bf2(c.z, c.w));
        }
    }

    // ---- V transpose via LDS ----
    {
        const float* vsrc = V + (((size_t)(b * SLEN + s0 + sl) * NHKV + h) * DIM) + dq;
        float4* ld = (float4*)&vt_s[sl * 132 + dq];
        #pragma unroll
        for (int i = 0; i < 8; ++i) ld[i] = ((const float4*)vsrc)[i];
    }
    __syncthreads();
    #pragma unroll
    for (int pass = 0; pass < 2; ++pass) {
        const int dl = (threadIdx.x >> 2) + pass * 64;   // 0..127
        const int sw = (threadIdx.x & 3) * 16;           // 0,16,32,48
        unsigned pk[8];
        #pragma unroll
        for (int m = 0; m < 8; ++m)
            pk[m] = pack_bf2(vt_s[(sw + 2 * m) * 132 + dl],
                             vt_s[(sw + 2 * m + 1) * 132 + dl]);
        unsigned short* dst = Vt + (((size_t)(b * NHKV + h) * DIM) + dl) * SLEN + s0 + sw;
        ((uint4*)dst)[0] = make_uint4(pk[0], pk[1], pk[2], pk[3]);
        ((uint4*)dst)[1] = make_uint4(pk[4], pk[5], pk[6], pk[7]);
    }
}

// ---------------------------------------------------------------------------
// Merged-head band-block MFMA flash attention (r7/r9 structure: 8 waves x
// 16 rows x 512 thr; TLP > per-wave efficiency, proven r1/r3/r8).
// Block = one 64-row band serving BOTH q-heads of a KV head: 8 waves =
// 2 hq x 4 sixteen-row tiles. Complementary band pairing (bid, bid+256 ->
// bands 7-ps, ps) balances per-CU makespan.
// MASK IS FULLY LANE-LOCAL (new r10): bidir-allowed(q,k) <=> k in
// [rs[q], re[q]] — run-id lookup rs[k] is redundant since the run containing
// q is exactly the maximal interval [rs[q], re[q]]; empty interval when
// mask[q]==0 (rs=-1, re=-2). Removes the per-tile rs[k0+lane] staging load
// and 16 ds_bpermute/wave/tile from the QK->exp2 critical path (-25% LDS
// instructions per tile).
// Swapped QK: sfr = mfma_16x16x32(K-frag, Q-frag) -> lane n holds
// P[qrow=n][key=c*16+quad*4+g] = A-frag of v_mfma_f32_16x16x16_bf16.
// P: register -> cvt -> MFMA. No P LDS.
// K/V: global_load_lds dbuf, 16B-granule XOR swizzle (pre-swizzled source,
// same XOR on read). LDS 64 KB -> 2 blocks/CU = 16 waves/CU.
// __launch_bounds__(512,2): empirical VGPR cap = 256/arg2 = 128, no spills.
// ---------------------------------------------------------------------------
__global__ __launch_bounds__(512, 2) void attn_fwd(
    const float* __restrict__ Q, const unsigned short* __restrict__ KbP,
    const unsigned short* __restrict__ VtP, const int* __restrict__ rs,
    const int* __restrict__ re, const int* __restrict__ csp,
    float* __restrict__ Out)
{
    const int tid  = threadIdx.x;
    const int wid  = tid >> 6;     // 0..7
    const int lane = tid & 63;
    const int quad = lane >> 4;
    const int n    = lane & 15;

    // decode: h = xcd (per-XCD K/V = 2 MB L2); bands paired 7-ps <-> ps
    const int bid   = blockIdx.x;          // 0..511
    const int h     = bid & 7;
    const int b     = (bid >> 3) & 1;
    const int chunk = (bid >> 4) & 3;
    const int ps    = (bid >> 6) & 3;
    const int sel   = (bid >> 8) & 1;
    const int band  = sel ? ps : 7 - ps;
    const int hq    = h * 2 + (wid & 1);   // wave-level head select
    const int wt    = wid >> 1;            // 0..3: 16-row tile within band
    const int r0 = chunk * SEG + band * 64 + wt * 16;

    __shared__ unsigned pool[2 * KTD + 2 * VTD];   // 65536 B

    // 1/sqrt(128) * log2(e): fold exp->exp2 into Q scaling
    const float scale = 0.08838834764831845f * 1.4426950408889634f;
    const int cs = csp[0];

    const int* rsb = rs + b * SLEN;
    const int* reb = re + b * SLEN;

    // per-row info: lane n -> row r0+n (duplicated across quads)
    const int row  = r0 + n;
    const int rsvq = rsb[row];             // run start of my row (-1 if none)
    const int revq = reb[row];             // run end of my row   (-2 if none)
    const int csrq = (row / cs) * cs;      // chunk start of my row
    int lo_rt, hi_rt;
    {
        int lo = csrq; if (rsvq >= 0 && rsvq < lo) lo = rsvq;
        int hi = row;  if (revq > hi) hi = revq;
        #pragma unroll
        for (int off = 8; off > 0; off >>= 1) {
            lo = min(lo, __shfl_xor(lo, off, 64));
            hi = max(hi, __shfl_xor(hi, off, 64));
        }
        lo_rt = lo; hi_rt = hi;
    }
    const int cshi = ((r0 + 15) / cs) * cs;

    // Q B-frags (scaled): qa[kb] holds Q[row n][d=kb*32+quad*8+j]
    bf16x8 qa[4];
    {
        const float* qp = Q + (((size_t)(b * SLEN + row) * NHQ + hq) * DIM) + quad * 8;
        #pragma unroll
        for (int kb = 0; kb < 4; ++kb) {
            float4 f0 = *(const float4*)(qp + kb * 32);
            float4 f1 = *(const float4*)(qp + kb * 32 + 4);
            bf16x8 a;
            a[0] = f2bf(f0.x * scale); a[1] = f2bf(f0.y * scale);
            a[2] = f2bf(f0.z * scale); a[3] = f2bf(f0.w * scale);
            a[4] = f2bf(f1.x * scale); a[5] = f2bf(f1.y * scale);
            a[6] = f2bf(f1.z * scale); a[7] = f2bf(f1.w * scale);
            qa[kb] = a;
        }
    }

    // block k-range = union over 8 waves (through pool, pre-staging)
    int lo_blk, hi_blk;
    {
        int* sred = (int*)pool;
        if (lane == 0) { sred[wid * 2] = lo_rt; sred[wid * 2 + 1] = hi_rt; }
        __syncthreads();
        int lo = 0x7fffffff, hi = 0;
        #pragma unroll
        for (int i = 0; i < 8; ++i) {
            lo = min(lo, sred[2 * i]);
            hi = max(hi, sred[2 * i + 1]);
        }
        __syncthreads();
        lo_blk = lo & ~63;
        hi_blk = hi;
    }

    float lrow = 0.0f;
    f32x4 o[8];
    #pragma unroll
    for (int nb = 0; nb < 8; ++nb) o[nb] = (f32x4){0.f, 0.f, 0.f, 0.f};

    const unsigned short* KbB = KbP + (size_t)(b * NHKV + h) * SLEN * DIM;
    const unsigned short* VtB = VtP + (size_t)(b * NHKV + h) * DIM * SLEN;

    // staging: per-thread pre-swizzled source offsets (16B granule involution)
    const int kr0  = tid >> 4;                       // K rows 0..31 (+32)
    const int ksl  = (tid & 15) ^ (kr0 & 15);
    const size_t koff = (size_t)kr0 * DIM + ksl * 8;
    const int vr0  = tid >> 3;                       // V rows 0..63 (+64)
    const int vsl  = (tid & 7) ^ (vr0 & 7);
    const size_t voff = (size_t)vr0 * SLEN + vsl * 8;

    // ---- prime: stage tile0 into buf0 ----
    {
        const unsigned short* ks = KbB + (size_t)lo_blk * DIM + koff;
        const unsigned short* vs = VtB + lo_blk + voff;
        char* kl = (char*)pool;
        char* vl = (char*)pool + 32768;
        GLDS(ks,                     kl + tid * 16);
        GLDS(ks + (size_t)32 * DIM,  kl + 8192 + tid * 16);
        GLDS(vs,                     vl + tid * 16);
        GLDS(vs + (size_t)64 * SLEN, vl + 8192 + tid * 16);
    }
    __syncthreads();   // drains vmcnt -> buf0 ready

    int bufi = 0;
    for (int k0 = lo_blk; k0 <= hi_blk; k0 += 64, bufi ^= 1) {
        // ---- issue stage for next tile into buf^1 ----
        if (k0 + 64 <= hi_blk) {
            const int kn0 = k0 + 64;
            const unsigned short* ks = KbB + (size_t)kn0 * DIM + koff;
            const unsigned short* vs = VtB + kn0 + voff;
            char* kl = (char*)pool + (bufi ^ 1) * 16384;
            char* vl = (char*)pool + 32768 + (bufi ^ 1) * 16384;
            GLDS(ks,                     kl + tid * 16);
            GLDS(ks + (size_t)32 * DIM,  kl + 8192 + tid * 16);
            GLDS(vs,                     vl + tid * 16);
            GLDS(vs + (size_t)64 * SLEN, vl + 8192 + tid * 16);
        }

        if ((k0 + 63 >= lo_rt) && (k0 <= hi_rt)) {
            const short* ktb = (const short*)(pool + bufi * KTD);
            const short* vtb = (const short*)(pool + 2 * KTD + bufi * VTD);

            // ---- S^T = mfma(K,Q): sfr[c][g] = S[qrow n][key k0+c*16+quad*4+g]
            f32x4 sfr[4];
            #pragma unroll
            for (int c = 0; c < 4; ++c) sfr[c] = (f32x4){0.f, 0.f, 0.f, 0.f};
            __builtin_amdgcn_s_setprio(1);
            #pragma unroll
            for (int c = 0; c < 4; ++c) {
                #pragma unroll
                for (int kb = 0; kb < 4; ++kb) {
                    const bf16x8 kf = *(const bf16x8*)(ktb +
                        (c * 16 + n) * DIM + (((kb * 4 + quad) ^ n) * 8));
                    sfr[c] = __builtin_amdgcn_mfma_f32_16x16x32_bf16(kf, qa[kb], sfr[c], 0, 0, 0);
                }
            }
            __builtin_amdgcn_s_setprio(0);

            // ---- mask: FULLY lane-local interval tests (no rs[k] gather) ----
            // allowed(row,k) = (csrq <= k <= row)  [chunk-causal]
            //               || (rsvq <= k <= revq)  [same run; empty if mask=0]
            const bool fullc = (k0 >= cshi) && (k0 + 63 <= r0);
            if (!fullc) {
                #pragma unroll
                for (int c = 0; c < 4; ++c) {
                    #pragma unroll
                    for (int g = 0; g < 4; ++g) {
                        const int kcl = k0 + c * 16 + quad * 4 + g;
                        const bool ok = ((kcl >= csrq) && (kcl <= row)) ||
                                        ((kcl >= rsvq) && (kcl <= revq));
                        if (!ok) sfr[c][g] = -3.0e38f;   // exp2 -> 0
                    }
                }
            }

            // ---- p = exp2(s): registers only; pack to A-frags ----
            bf16x4 pa[4];
            #pragma unroll
            for (int c = 0; c < 4; ++c) {
                float p0 = fast_exp2(sfr[c][0]);
                float p1 = fast_exp2(sfr[c][1]);
                float p2 = fast_exp2(sfr[c][2]);
                float p3 = fast_exp2(sfr[c][3]);
                lrow += (p0 + p1) + (p2 + p3);
                uint2 ww = make_uint2(pack_bf2(p0, p1), pack_bf2(p2, p3));
                pa[c] = __builtin_bit_cast(bf16x4, ww);
            }

            // ---- O += P V via 16x16x16 (A = registers, B = V^T from LDS) ----
            __builtin_amdgcn_s_setprio(1);
            #pragma unroll
            for (int c = 0; c < 4; ++c) {
                #pragma unroll
                for (int nb = 0; nb < 8; ++nb) {
                    const bf16x4 vb = *(const bf16x4*)(vtb +
                        (nb * 16 + n) * 64 + (((c * 2 + (quad >> 1)) ^ (n & 7)) * 8)
                        + (quad & 1) * 4);
                    o[nb] = mfma16(pa[c], vb, o[nb]);
                }
            }
            __builtin_amdgcn_s_setprio(0);
        }

        __syncthreads();   // drains next-tile loads; releases buf[bufi]
    }

    // ---- epilogue: row-sum over quads, redistribute inv, store ----
    lrow += __shfl_xor(lrow, 16, 64);
    lrow += __shfl_xor(lrow, 32, 64);
    const float inv = 1.0f / lrow;     // lane holds inv for row n
    #pragma unroll
    for (int g = 0; g < 4; ++g) {
        const float invg = __shfl(inv, quad * 4 + g, 64);
        const int r = r0 + quad * 4 + g;
        float* op = Out + ((size_t)(b * SLEN + r) * NHQ + hq) * DIM + n;
        #pragma unroll
        for (int nb = 0; nb < 8; ++nb)
            op[nb * 16] = o[nb][g] * invg;
    }
}

extern "C" void kernel_launch(void* const* d_in, const int* in_sizes, int n_in,
                              void* d_out, int out_size, void* d_ws, size_t ws_size,
                              hipStream_t stream) {
    const float* q  = (const float*)d_in[0];
    const float* k  = (const float*)d_in[1];
    const float* v  = (const float*)d_in[2];
    const int*   bm = (const int*)d_in[3];
    const int*   cs = (const int*)d_in[4];
    float* out = (float*)d_out;

    int* rs = (int*)d_ws;
    int* re = rs + BATCH * SLEN;
    unsigned short* Kb = (unsigned short*)((char*)d_ws + 32768);
    unsigned short* Vt = Kb + (size_t)BATCH * NHKV * SLEN * DIM;

    hipLaunchKernelGGL(conv_kv, dim3(BATCH * NHKV * (SLEN / 64) + BATCH * 8), dim3(256),
                       0, stream, k, v, Kb, Vt, bm, rs, re);
    hipLaunchKernelGGL(attn_fwd, dim3(512), dim3(512), 0, stream,
                       q, Kb, Vt, rs, re, cs, out);
}